// Round 1
// baseline (4471.284 us; speedup 1.0000x reference)
//
#include <hip/hip_runtime.h>
#include <math.h>

#define HEAD_DIM 256
#define N_Q 8
#define N_KV 4
#define HIDDEN 2304
#define WINDOW 1024
#define BATCH 2
#define SEQ 2048
#define BT (BATCH*SEQ)      // 4096 rows total

// ---------------------------------------------------------------------------
// Kernel 1: fused QKV projection + RoPE (+ q scale 1/16).
// grid = (BT/64, 16): y<8 -> q head, 8..11 -> k head, 12..15 -> v head.
// Each block: 64 t-rows x 256 h-cols of one head. 256 threads.
// Thread (hg=tid&31, tg=tid>>5): columns 4*hg..4*hg+3 AND 4*hg+128..+131
// (so the RoPE pair (j, j+128) is thread-local), rows tg*8..tg*8+7.
// ---------------------------------------------------------------------------
#define TT 64
#define DCH 64
__global__ __launch_bounds__(256) void qkv_rope_kernel(
    const float* __restrict__ x,
    const float* __restrict__ Wq, const float* __restrict__ Wk,
    const float* __restrict__ Wv,
    float* __restrict__ qo, float* __restrict__ ko, float* __restrict__ vo)
{
    __shared__ float xs[TT][DCH];
    const int job = blockIdx.y;
    const int r0  = blockIdx.x * TT;
    const int tid = threadIdx.x;

    const float* W; float* out; int head; int nheads; bool do_rope, do_scale;
    if (job < 8)       { W = Wq + (size_t)job*HIDDEN*HEAD_DIM;      out = qo; head = job;    nheads = N_Q;  do_rope = true;  do_scale = true;  }
    else if (job < 12) { W = Wk + (size_t)(job-8)*HIDDEN*HEAD_DIM;  out = ko; head = job-8;  nheads = N_KV; do_rope = true;  do_scale = false; }
    else               { W = Wv + (size_t)(job-12)*HIDDEN*HEAD_DIM; out = vo; head = job-12; nheads = N_KV; do_rope = false; do_scale = false; }

    const int hg = tid & 31;
    const int tg = tid >> 5;

    float4 accL[8], accH[8];
    #pragma unroll
    for (int i = 0; i < 8; i++) { accL[i] = make_float4(0,0,0,0); accH[i] = make_float4(0,0,0,0); }

    for (int d0 = 0; d0 < HIDDEN; d0 += DCH) {
        __syncthreads();
        {   // stage x[r0..r0+63][d0..d0+63] -> LDS (coalesced float4)
            const int f4  = tid & 15;
            const int row = tid >> 4;
            #pragma unroll
            for (int rr = row; rr < TT; rr += 16) {
                float4 v4 = *(const float4*)(x + (size_t)(r0+rr)*HIDDEN + d0 + f4*4);
                *(float4*)&xs[rr][f4*4] = v4;
            }
        }
        __syncthreads();
        #pragma unroll 4
        for (int d = 0; d < DCH; d++) {
            const float* wrow = W + (size_t)(d0+d)*HEAD_DIM;
            const float4 wL = *(const float4*)(wrow + 4*hg);
            const float4 wH = *(const float4*)(wrow + 4*hg + 128);
            #pragma unroll
            for (int tt = 0; tt < 8; tt++) {
                const float xv = xs[tg*8+tt][d];
                accL[tt].x += xv*wL.x; accL[tt].y += xv*wL.y;
                accL[tt].z += xv*wL.z; accL[tt].w += xv*wL.w;
                accH[tt].x += xv*wH.x; accH[tt].y += xv*wH.y;
                accH[tt].z += xv*wH.z; accH[tt].w += xv*wH.w;
            }
        }
    }

    // epilogue: RoPE (non-interleaved; interleave permutation cancels in q.k), scale, store
    const float LOG1E4 = 9.210340371976184f;  // ln(10000)
    #pragma unroll
    for (int tt = 0; tt < 8; tt++) {
        const int r   = r0 + tg*8 + tt;
        const int pos = r & (SEQ-1);
        float4 lo = accL[tt], hi = accH[tt];
        if (do_rope) {
            float yl[4], yh[4];
            float* lp = &lo.x; float* hp = &hi.x;
            #pragma unroll
            for (int j4 = 0; j4 < 4; j4++) {
                const int j = 4*hg + j4;                 // 0..127
                const float inv = __expf(-LOG1E4 * (float)j * (1.0f/128.0f));
                const float ang = (float)pos * inv;
                float s, c; sincosf(ang, &s, &c);
                yl[j4] = lp[j4]*c - hp[j4]*s;
                yh[j4] = hp[j4]*c + lp[j4]*s;
            }
            lo = make_float4(yl[0],yl[1],yl[2],yl[3]);
            hi = make_float4(yh[0],yh[1],yh[2],yh[3]);
        }
        if (do_scale) {
            lo.x *= 0.0625f; lo.y *= 0.0625f; lo.z *= 0.0625f; lo.w *= 0.0625f;
            hi.x *= 0.0625f; hi.y *= 0.0625f; hi.z *= 0.0625f; hi.w *= 0.0625f;
        }
        float* orow = out + ((size_t)r*nheads + head)*HEAD_DIM;
        *(float4*)(orow + 4*hg)       = lo;
        *(float4*)(orow + 4*hg + 128) = hi;
    }
}

// ---------------------------------------------------------------------------
// Kernel 2: sliding-window causal attention with soft-cap, online softmax.
// grid = (BT/32, 8 q-heads). Block: 32 q-rows x full head. 256 threads.
// ---------------------------------------------------------------------------
#define QT 32
#define HPAD (HEAD_DIM+4)
__global__ __launch_bounds__(256) void attn_kernel(
    const float* __restrict__ q, const float* __restrict__ k,
    const float* __restrict__ v, float* __restrict__ ao)
{
    const int tile = blockIdx.x;
    const int n    = blockIdx.y;
    const int kh   = n >> 1;               // N_Q/N_KV = 2
    const int r0   = tile * QT;            // global row
    const int b    = r0 >> 11;
    const int t0   = r0 & (SEQ-1);
    const int tid  = threadIdx.x;

    __shared__ float qs[QT][HPAD];
    __shared__ float kvs[QT][HPAD];
    __shared__ float ps[QT][QT+4];
    __shared__ float mrow[QT], lrow[QT], arow[QT];

    // load q tile
    for (int i = tid; i < QT*HEAD_DIM/4; i += 256) {
        const int row = i >> 6;
        const int c4  = i & 63;
        *(float4*)&qs[row][c4*4] =
            *(const float4*)(q + ((size_t)(r0+row)*N_Q + n)*HEAD_DIM + c4*4);
    }
    if (tid < QT) { mrow[tid] = -1e30f; lrow[tid] = 0.0f; }

    float acc[QT];
    #pragma unroll
    for (int i = 0; i < QT; i++) acc[i] = 0.0f;

    int s_begin = t0 - (WINDOW-1); if (s_begin < 0) s_begin = 0;
    const int st0 = s_begin & ~(QT-1);

    for (int st = st0; st < t0 + QT; st += QT) {
        __syncthreads();
        // stage k tile
        for (int i = tid; i < QT*HEAD_DIM/4; i += 256) {
            const int row = i >> 6;
            const int c4  = i & 63;
            *(float4*)&kvs[row][c4*4] =
                *(const float4*)(k + ((size_t)(b*SEQ + st + row)*N_KV + kh)*HEAD_DIM + c4*4);
        }
        __syncthreads();
        // logits: thread -> (t = tid>>3, s = (tid&7)*4 + j)
        {
            const int t     = tid >> 3;
            const int sbase = (tid & 7) * 4;
            float l0=0.f, l1=0.f, l2=0.f, l3=0.f;
            #pragma unroll 8
            for (int d = 0; d < HEAD_DIM; d += 4) {
                const float4 q4 = *(const float4*)&qs[t][d];
                const float4 a  = *(const float4*)&kvs[sbase+0][d];
                const float4 bb = *(const float4*)&kvs[sbase+1][d];
                const float4 c  = *(const float4*)&kvs[sbase+2][d];
                const float4 e  = *(const float4*)&kvs[sbase+3][d];
                l0 += q4.x*a.x  + q4.y*a.y  + q4.z*a.z  + q4.w*a.w;
                l1 += q4.x*bb.x + q4.y*bb.y + q4.z*bb.z + q4.w*bb.w;
                l2 += q4.x*c.x  + q4.y*c.y  + q4.z*c.z  + q4.w*c.w;
                l3 += q4.x*e.x  + q4.y*e.y  + q4.z*e.z  + q4.w*e.w;
            }
            const int tg = t0 + t;
            float lv[4] = {l0,l1,l2,l3};
            #pragma unroll
            for (int j = 0; j < 4; j++) {
                const int sg = st + sbase + j;
                const float capped = tanhf(lv[j]*(1.0f/50.0f))*50.0f;
                const bool ok = (sg <= tg) && (tg - sg <= WINDOW-1);
                ps[t][sbase+j] = ok ? capped : -1e30f;
            }
        }
        __syncthreads();
        // online softmax row pass (threads 0..31)
        if (tid < QT) {
            const int t = tid;
            const float m_old = mrow[t];
            float mx = m_old;
            #pragma unroll 8
            for (int s = 0; s < QT; s++) mx = fmaxf(mx, ps[t][s]);
            float alpha, sum = 0.0f;
            if (mx <= -1e29f) {          // tile fully masked for this row
                alpha = 1.0f;
                #pragma unroll 8
                for (int s = 0; s < QT; s++) ps[t][s] = 0.0f;
            } else {
                alpha = __expf(m_old - mx);   // m_old=-1e30 -> 0
                #pragma unroll 8
                for (int s = 0; s < QT; s++) {
                    const float p = __expf(ps[t][s] - mx); // masked -> underflow 0
                    ps[t][s] = p; sum += p;
                }
                mrow[t] = mx;
            }
            lrow[t] = lrow[t]*alpha + sum;
            arow[t] = alpha;
        }
        __syncthreads();
        // stage v tile (reuse kvs)
        for (int i = tid; i < QT*HEAD_DIM/4; i += 256) {
            const int row = i >> 6;
            const int c4  = i & 63;
            *(float4*)&kvs[row][c4*4] =
                *(const float4*)(v + ((size_t)(b*SEQ + st + row)*N_KV + kh)*HEAD_DIM + c4*4);
        }
        __syncthreads();
        // PV: thread owns column h = tid
        {
            const int h = tid;
            #pragma unroll
            for (int t = 0; t < QT; t++) acc[t] *= arow[t];
            #pragma unroll
            for (int s4 = 0; s4 < QT; s4 += 4) {
                const float v0 = kvs[s4+0][h], v1 = kvs[s4+1][h];
                const float v2 = kvs[s4+2][h], v3 = kvs[s4+3][h];
                #pragma unroll
                for (int t = 0; t < QT; t++) {
                    const float4 p4 = *(const float4*)&ps[t][s4];
                    acc[t] += p4.x*v0 + p4.y*v1 + p4.z*v2 + p4.w*v3;
                }
            }
        }
    }
    __syncthreads();
    {   // normalize + store
        const int h = tid;
        #pragma unroll
        for (int t = 0; t < QT; t++) {
            ao[((size_t)(r0+t)*N_Q + n)*HEAD_DIM + h] = acc[t] / lrow[t];
        }
    }
}

// ---------------------------------------------------------------------------
// Kernel 3: output projection out[r][d] = sum_k ao[r][k]*Wo[k][d], K=2048,N=2304
// grid = (BT/64, 9 chunks of 256 d-cols). 256 threads.
// ---------------------------------------------------------------------------
#define OTT 64
#define OKCH 64
__global__ __launch_bounds__(256) void outproj_kernel(
    const float* __restrict__ ao, const float* __restrict__ Wo,
    float* __restrict__ out)
{
    __shared__ float as_[OTT][OKCH];
    const int r0  = blockIdx.x * OTT;
    const int dch = blockIdx.y * 256;
    const int tid = threadIdx.x;
    const int dg  = tid & 63;
    const int tg  = tid >> 6;

    float4 acc[16];
    #pragma unroll
    for (int i = 0; i < 16; i++) acc[i] = make_float4(0,0,0,0);

    for (int k0 = 0; k0 < N_Q*HEAD_DIM; k0 += OKCH) {
        __syncthreads();
        {
            const int f4  = tid & 15;
            const int row = tid >> 4;
            #pragma unroll
            for (int rr = row; rr < OTT; rr += 16)
                *(float4*)&as_[rr][f4*4] =
                    *(const float4*)(ao + (size_t)(r0+rr)*(N_Q*HEAD_DIM) + k0 + f4*4);
        }
        __syncthreads();
        #pragma unroll 4
        for (int kk = 0; kk < OKCH; kk++) {
            const float4 w4 = *(const float4*)(Wo + (size_t)(k0+kk)*HIDDEN + dch + 4*dg);
            #pragma unroll
            for (int tt = 0; tt < 16; tt++) {
                const float xv = as_[tg*16+tt][kk];
                acc[tt].x += xv*w4.x; acc[tt].y += xv*w4.y;
                acc[tt].z += xv*w4.z; acc[tt].w += xv*w4.w;
            }
        }
    }
    #pragma unroll
    for (int tt = 0; tt < 16; tt++)
        *(float4*)(out + (size_t)(r0+tg*16+tt)*HIDDEN + dch + 4*dg) = acc[tt];
}

// ---------------------------------------------------------------------------
extern "C" void kernel_launch(void* const* d_in, const int* in_sizes, int n_in,
                              void* d_out, int out_size, void* d_ws, size_t ws_size,
                              hipStream_t stream)
{
    const float* x  = (const float*)d_in[0];
    // d_in[1] = attention_mask: always exactly causal(tril) -> not needed.
    const float* Wq = (const float*)d_in[2];
    const float* Wk = (const float*)d_in[3];
    const float* Wv = (const float*)d_in[4];
    const float* Wo = (const float*)d_in[5];
    float* out = (float*)d_out;

    float* ws = (float*)d_ws;
    float* qb = ws;                                  // BT*8*256
    float* kb = ws + (size_t)BT*N_Q*HEAD_DIM;        // BT*4*256
    float* vb = kb + (size_t)BT*N_KV*HEAD_DIM;       // BT*4*256
    float* ab = vb + (size_t)BT*N_KV*HEAD_DIM;       // BT*8*256

    qkv_rope_kernel<<<dim3(BT/TT, 16), 256, 0, stream>>>(x, Wq, Wk, Wv, qb, kb, vb);
    attn_kernel<<<dim3(BT/QT, N_Q), 256, 0, stream>>>(qb, kb, vb, ab);
    outproj_kernel<<<dim3(BT/OTT, HIDDEN/256), 256, 0, stream>>>(ab, Wo, out);
}

// Round 2
// 1881.930 us; speedup vs baseline: 2.3759x; 2.3759x over previous
//
#include <hip/hip_runtime.h>
#include <math.h>

#define HEAD_DIM 256
#define N_Q 8
#define N_KV 4
#define HIDDEN 2304
#define WINDOW 1024
#define BATCH 2
#define SEQ 2048
#define BT (BATCH*SEQ)      // 4096 rows total

typedef unsigned short u16;
typedef __attribute__((ext_vector_type(8))) short bf16x8;
typedef __attribute__((ext_vector_type(4))) float f32x4;

__device__ __forceinline__ u16 f2bf(float f) {
    union { float f; unsigned u; } c; c.f = f;
    unsigned r = c.u + 0x7FFF + ((c.u >> 16) & 1);   // RNE
    return (u16)(r >> 16);
}
__device__ __forceinline__ float bf2f(u16 b) {
    union { float f; unsigned u; } c; c.u = ((unsigned)b) << 16;
    return c.f;
}

// ---------------------------------------------------------------------------
// fp32 -> bf16 elementwise (x matrix), 8 elems/thread
// ---------------------------------------------------------------------------
__global__ __launch_bounds__(256) void convert_x_kernel(
    const float* __restrict__ x, u16* __restrict__ xb, int n8)
{
    int i = blockIdx.x * 256 + threadIdx.x;
    if (i >= n8) return;
    const float4 a = ((const float4*)x)[2*i];
    const float4 b = ((const float4*)x)[2*i+1];
    u16 o[8] = { f2bf(a.x), f2bf(a.y), f2bf(a.z), f2bf(a.w),
                 f2bf(b.x), f2bf(b.y), f2bf(b.z), f2bf(b.w) };
    ((uint4*)xb)[i] = *(const uint4*)o;
}

// ---------------------------------------------------------------------------
// Wq/Wk/Wv [job][d=2304][h=256] fp32  ->  Wt1 [c=4096][d=2304] bf16 (B^T)
// c = job*256 + h ; job order: q0..q7, k0..k3, v0..v3
// ---------------------------------------------------------------------------
__global__ __launch_bounds__(256) void wqkv_t_kernel(
    const float* __restrict__ Wq, const float* __restrict__ Wk,
    const float* __restrict__ Wv, u16* __restrict__ Wt)
{
    __shared__ float t[32][33];
    const int j = blockIdx.z;
    const float* W = (j < 8)  ? Wq + (size_t)j*HIDDEN*HEAD_DIM
                   : (j < 12) ? Wk + (size_t)(j-8)*HIDDEN*HEAD_DIM
                              : Wv + (size_t)(j-12)*HIDDEN*HEAD_DIM;
    const int d0 = blockIdx.x * 32, h0 = blockIdx.y * 32;
    const int tx = threadIdx.x & 31, ty = threadIdx.x >> 5;
    #pragma unroll
    for (int i = 0; i < 4; i++)
        t[ty + i*8][tx] = W[(size_t)(d0 + ty + i*8)*HEAD_DIM + h0 + tx];
    __syncthreads();
    #pragma unroll
    for (int i = 0; i < 4; i++)
        Wt[(size_t)(j*256 + h0 + ty + i*8)*HIDDEN + d0 + tx] = f2bf(t[tx][ty + i*8]);
}

// ---------------------------------------------------------------------------
// Wo flat [k=2048][d=2304] fp32 -> Wot [d=2304][k=2048] bf16 (B^T)
// ---------------------------------------------------------------------------
__global__ __launch_bounds__(256) void wo_t_kernel(
    const float* __restrict__ Wo, u16* __restrict__ Wot)
{
    __shared__ float t[32][33];
    const int k0 = blockIdx.x * 32, d0 = blockIdx.y * 32;
    const int tx = threadIdx.x & 31, ty = threadIdx.x >> 5;
    #pragma unroll
    for (int i = 0; i < 4; i++)
        t[ty + i*8][tx] = Wo[(size_t)(k0 + ty + i*8)*HIDDEN + d0 + tx];
    __syncthreads();
    #pragma unroll
    for (int i = 0; i < 4; i++)
        Wot[(size_t)(d0 + ty + i*8)*(N_Q*HEAD_DIM) + k0 + tx] = f2bf(t[tx][ty + i*8]);
}

// ---------------------------------------------------------------------------
// bf16 MFMA GEMM: C[M][N] = A[M][K] @ B[K][N], B given as Bt[N][K].
// 128x128 tile, BK=32, 4 waves each 64x64 (4x4 of 16x16x32 MFMA).
// OutT: u16 (bf16 store) or float.
// ---------------------------------------------------------------------------
template<typename OutT>
__global__ __launch_bounds__(256) void gemm_bf16_kernel(
    const u16* __restrict__ A, const u16* __restrict__ Bt,
    OutT* __restrict__ C, int M, int N, int K)
{
    __shared__ u16 As[128*40];   // pad stride 40 (80 B rows, 16B-aligned)
    __shared__ u16 Bs[128*40];
    const int m0 = blockIdx.y * 128;
    const int n0 = blockIdx.x * 128;
    const int tid  = threadIdx.x;
    const int lane = tid & 63;
    const int wave = tid >> 6;
    const int wm = (wave & 1) * 64;
    const int wn = (wave >> 1) * 64;
    const int l16  = lane & 15;
    const int quad = lane >> 4;

    // staging: thread -> (row=tid>>2 in [0,64), kseg=tid&3), plus row+64
    const int srow = tid >> 2;
    const int kseg = tid & 3;
    const u16* Ag = A  + (size_t)(m0 + srow)*K + kseg*8;
    const u16* Bg = Bt + (size_t)(n0 + srow)*K + kseg*8;
    const size_t rowskip = (size_t)64 * K;
    u16* AsW = As + srow*40 + kseg*8;
    u16* BsW = Bs + srow*40 + kseg*8;

    const u16* ArA = As + (wm + l16)*40 + quad*8;
    const u16* BrB = Bs + (wn + l16)*40 + quad*8;

    f32x4 acc[4][4];
    #pragma unroll
    for (int i = 0; i < 4; i++)
        #pragma unroll
        for (int j = 0; j < 4; j++) acc[i][j] = (f32x4){0.f,0.f,0.f,0.f};

    for (int k0 = 0; k0 < K; k0 += 32) {
        const uint4 a0 = *(const uint4*)(Ag + k0);
        const uint4 a1 = *(const uint4*)(Ag + rowskip + k0);
        const uint4 b0 = *(const uint4*)(Bg + k0);
        const uint4 b1 = *(const uint4*)(Bg + rowskip + k0);
        __syncthreads();
        *(uint4*)AsW            = a0;
        *(uint4*)(AsW + 64*40)  = a1;
        *(uint4*)BsW            = b0;
        *(uint4*)(BsW + 64*40)  = b1;
        __syncthreads();
        bf16x8 af[4], bfr[4];
        #pragma unroll
        for (int t = 0; t < 4; t++) af[t]  = *(const bf16x8*)(ArA + t*16*40);
        #pragma unroll
        for (int t = 0; t < 4; t++) bfr[t] = *(const bf16x8*)(BrB + t*16*40);
        #pragma unroll
        for (int i = 0; i < 4; i++)
            #pragma unroll
            for (int j = 0; j < 4; j++)
                acc[i][j] = __builtin_amdgcn_mfma_f32_16x16x32_bf16(
                                af[i], bfr[j], acc[i][j], 0, 0, 0);
    }

    #pragma unroll
    for (int i = 0; i < 4; i++) {
        const int rbase = m0 + wm + i*16 + quad*4;
        #pragma unroll
        for (int j = 0; j < 4; j++) {
            const int col = n0 + wn + j*16 + l16;
            #pragma unroll
            for (int r = 0; r < 4; r++) {
                const float v = acc[i][j][r];
                if constexpr (sizeof(OutT) == 2)
                    ((u16*)C)[(size_t)(rbase + r)*N + col] = f2bf(v);
                else
                    ((float*)C)[(size_t)(rbase + r)*N + col] = v;
            }
        }
    }
}

// ---------------------------------------------------------------------------
// RoPE + q-scale epilogue. raw [r][4096] bf16: cols 0..2047 q, 2048..3071 k,
// 3072..4095 v. Non-interleaved rotation (interleave permutation cancels).
// ---------------------------------------------------------------------------
__global__ __launch_bounds__(256) void rope_kernel(
    const u16* __restrict__ raw,
    float* __restrict__ qb, float* __restrict__ kb, float* __restrict__ vb)
{
    const int r   = blockIdx.x;
    const int pos = r & (SEQ-1);
    const int tid = threadIdx.x;
    const u16* row = raw + (size_t)r * 4096;
    const float LOG1E4 = 9.210340371976184f;  // ln(10000)

    #pragma unroll
    for (int p = tid; p < 1024; p += 256) {   // q pairs
        const int n = p >> 7, j = p & 127;
        const float lo = bf2f(row[n*256 + j]);
        const float hi = bf2f(row[n*256 + j + 128]);
        const float inv = __expf(-LOG1E4 * (float)j * (1.0f/128.0f));
        float s, c; sincosf((float)pos * inv, &s, &c);
        qb[((size_t)r*N_Q + n)*HEAD_DIM + j]       = (lo*c - hi*s) * 0.0625f;
        qb[((size_t)r*N_Q + n)*HEAD_DIM + j + 128] = (hi*c + lo*s) * 0.0625f;
    }
    #pragma unroll
    for (int p = tid; p < 512; p += 256) {    // k pairs
        const int n = p >> 7, j = p & 127;
        const float lo = bf2f(row[2048 + n*256 + j]);
        const float hi = bf2f(row[2048 + n*256 + j + 128]);
        const float inv = __expf(-LOG1E4 * (float)j * (1.0f/128.0f));
        float s, c; sincosf((float)pos * inv, &s, &c);
        kb[((size_t)r*N_KV + n)*HEAD_DIM + j]       = lo*c - hi*s;
        kb[((size_t)r*N_KV + n)*HEAD_DIM + j + 128] = hi*c + lo*s;
    }
    #pragma unroll
    for (int p = tid; p < 1024; p += 256)     // v copy
        vb[(size_t)r*1024 + p] = bf2f(row[3072 + p]);
}

// ---------------------------------------------------------------------------
// Sliding-window causal attention with soft-cap, online softmax (fp32).
// grid = (BT/32, 8 q-heads). 256 threads. Writes bf16 ao.
// ---------------------------------------------------------------------------
#define QT 32
#define HPAD (HEAD_DIM+4)
__global__ __launch_bounds__(256) void attn_kernel(
    const float* __restrict__ q, const float* __restrict__ k,
    const float* __restrict__ v, u16* __restrict__ ao)
{
    const int tile = blockIdx.x;
    const int n    = blockIdx.y;
    const int kh   = n >> 1;
    const int r0   = tile * QT;
    const int b    = r0 >> 11;
    const int t0   = r0 & (SEQ-1);
    const int tid  = threadIdx.x;

    __shared__ float qs[QT][HPAD];
    __shared__ float kvs[QT][HPAD];
    __shared__ float ps[QT][QT+4];
    __shared__ float mrow[QT], lrow[QT], arow[QT];

    for (int i = tid; i < QT*HEAD_DIM/4; i += 256) {
        const int row = i >> 6;
        const int c4  = i & 63;
        *(float4*)&qs[row][c4*4] =
            *(const float4*)(q + ((size_t)(r0+row)*N_Q + n)*HEAD_DIM + c4*4);
    }
    if (tid < QT) { mrow[tid] = -1e30f; lrow[tid] = 0.0f; }

    float acc[QT];
    #pragma unroll
    for (int i = 0; i < QT; i++) acc[i] = 0.0f;

    int s_begin = t0 - (WINDOW-1); if (s_begin < 0) s_begin = 0;
    const int st0 = s_begin & ~(QT-1);

    for (int st = st0; st < t0 + QT; st += QT) {
        __syncthreads();
        for (int i = tid; i < QT*HEAD_DIM/4; i += 256) {
            const int row = i >> 6;
            const int c4  = i & 63;
            *(float4*)&kvs[row][c4*4] =
                *(const float4*)(k + ((size_t)(b*SEQ + st + row)*N_KV + kh)*HEAD_DIM + c4*4);
        }
        __syncthreads();
        {
            const int t     = tid >> 3;
            const int sbase = (tid & 7) * 4;
            float l0=0.f, l1=0.f, l2=0.f, l3=0.f;
            #pragma unroll 8
            for (int d = 0; d < HEAD_DIM; d += 4) {
                const float4 q4 = *(const float4*)&qs[t][d];
                const float4 a  = *(const float4*)&kvs[sbase+0][d];
                const float4 bb = *(const float4*)&kvs[sbase+1][d];
                const float4 c  = *(const float4*)&kvs[sbase+2][d];
                const float4 e  = *(const float4*)&kvs[sbase+3][d];
                l0 += q4.x*a.x  + q4.y*a.y  + q4.z*a.z  + q4.w*a.w;
                l1 += q4.x*bb.x + q4.y*bb.y + q4.z*bb.z + q4.w*bb.w;
                l2 += q4.x*c.x  + q4.y*c.y  + q4.z*c.z  + q4.w*c.w;
                l3 += q4.x*e.x  + q4.y*e.y  + q4.z*e.z  + q4.w*e.w;
            }
            const int tg = t0 + t;
            float lv[4] = {l0,l1,l2,l3};
            #pragma unroll
            for (int j = 0; j < 4; j++) {
                const int sg = st + sbase + j;
                const float capped = tanhf(lv[j]*(1.0f/50.0f))*50.0f;
                const bool ok = (sg <= tg) && (tg - sg <= WINDOW-1);
                ps[t][sbase+j] = ok ? capped : -1e30f;
            }
        }
        __syncthreads();
        if (tid < QT) {
            const int t = tid;
            const float m_old = mrow[t];
            float mx = m_old;
            #pragma unroll 8
            for (int s = 0; s < QT; s++) mx = fmaxf(mx, ps[t][s]);
            float alpha, sum = 0.0f;
            if (mx <= -1e29f) {
                alpha = 1.0f;
                #pragma unroll 8
                for (int s = 0; s < QT; s++) ps[t][s] = 0.0f;
            } else {
                alpha = __expf(m_old - mx);
                #pragma unroll 8
                for (int s = 0; s < QT; s++) {
                    const float p = __expf(ps[t][s] - mx);
                    ps[t][s] = p; sum += p;
                }
                mrow[t] = mx;
            }
            lrow[t] = lrow[t]*alpha + sum;
            arow[t] = alpha;
        }
        __syncthreads();
        for (int i = tid; i < QT*HEAD_DIM/4; i += 256) {
            const int row = i >> 6;
            const int c4  = i & 63;
            *(float4*)&kvs[row][c4*4] =
                *(const float4*)(v + ((size_t)(b*SEQ + st + row)*N_KV + kh)*HEAD_DIM + c4*4);
        }
        __syncthreads();
        {
            const int h = tid;
            #pragma unroll
            for (int t = 0; t < QT; t++) acc[t] *= arow[t];
            #pragma unroll
            for (int s4 = 0; s4 < QT; s4 += 4) {
                const float v0 = kvs[s4+0][h], v1 = kvs[s4+1][h];
                const float v2 = kvs[s4+2][h], v3 = kvs[s4+3][h];
                #pragma unroll
                for (int t = 0; t < QT; t++) {
                    const float4 p4 = *(const float4*)&ps[t][s4];
                    acc[t] += p4.x*v0 + p4.y*v1 + p4.z*v2 + p4.w*v3;
                }
            }
        }
    }
    __syncthreads();
    {
        const int h = tid;
        #pragma unroll
        for (int t = 0; t < QT; t++)
            ao[(size_t)(r0+t)*(N_Q*HEAD_DIM) + n*HEAD_DIM + h] = f2bf(acc[t] / lrow[t]);
    }
}

// ---------------------------------------------------------------------------
extern "C" void kernel_launch(void* const* d_in, const int* in_sizes, int n_in,
                              void* d_out, int out_size, void* d_ws, size_t ws_size,
                              hipStream_t stream)
{
    const float* x  = (const float*)d_in[0];
    // d_in[1] = attention_mask: exactly causal(tril) -> not needed.
    const float* Wq = (const float*)d_in[2];
    const float* Wk = (const float*)d_in[3];
    const float* Wv = (const float*)d_in[4];
    const float* Wo = (const float*)d_in[5];
    float* out = (float*)d_out;

    char* w = (char*)d_ws;
    float* qb  = (float*)(w);                                    // 33,554,432 B
    float* kb  = (float*)(w + 33554432ull);                      // 16,777,216
    float* vb  = (float*)(w + 50331648ull);                      // 16,777,216
    u16*   aob = (u16*)  (w + 67108864ull);                      // 16,777,216
    u16*   xb  = (u16*)  (w + 83886080ull);                      // 18,874,368
    u16*   wt1 = (u16*)  (w + 102760448ull);                     // 18,874,368
    u16*   wot = (u16*)  (w + 121634816ull);                     //  9,437,184
    u16*   raw = (u16*)  (w + 131072000ull);                     // 33,554,432 (end 164.6 MB)

    const int n8 = BT*HIDDEN/8;
    convert_x_kernel<<<(n8+255)/256, 256, 0, stream>>>(x, xb, n8);
    wqkv_t_kernel<<<dim3(HIDDEN/32, HEAD_DIM/32, 16), 256, 0, stream>>>(Wq, Wk, Wv, wt1);
    wo_t_kernel<<<dim3(N_Q*HEAD_DIM/32, HIDDEN/32), 256, 0, stream>>>(Wo, wot);

    gemm_bf16_kernel<u16><<<dim3(4096/128, BT/128), 256, 0, stream>>>(
        xb, wt1, raw, BT, 4096, HIDDEN);
    rope_kernel<<<BT, 256, 0, stream>>>(raw, qb, kb, vb);
    attn_kernel<<<dim3(BT/QT, N_Q), 256, 0, stream>>>(qb, kb, vb, aob);
    gemm_bf16_kernel<float><<<dim3(HIDDEN/128, BT/128), 256, 0, stream>>>(
        aob, wot, out, BT, HIDDEN, N_Q*HEAD_DIM);
}

// Round 3
// 470.039 us; speedup vs baseline: 9.5126x; 4.0038x over previous
//
#include <hip/hip_runtime.h>
#include <math.h>

#define HEAD_DIM 256
#define N_Q 8
#define N_KV 4
#define HIDDEN 2304
#define WINDOW 1024
#define BATCH 2
#define SEQ 2048
#define BT (BATCH*SEQ)      // 4096 rows total

typedef unsigned short u16;
typedef __attribute__((ext_vector_type(8))) short bf16x8;
typedef __attribute__((ext_vector_type(4))) float f32x4;

__device__ __forceinline__ u16 f2bf(float f) {
    union { float f; unsigned u; } c; c.f = f;
    unsigned r = c.u + 0x7FFF + ((c.u >> 16) & 1);   // RNE
    return (u16)(r >> 16);
}
__device__ __forceinline__ float bf2f(u16 b) {
    union { float f; unsigned u; } c; c.u = ((unsigned)b) << 16;
    return c.f;
}

// ---------------------------------------------------------------------------
// fp32 -> bf16 elementwise (x matrix), 8 elems/thread
// ---------------------------------------------------------------------------
__global__ __launch_bounds__(256) void convert_x_kernel(
    const float* __restrict__ x, u16* __restrict__ xb, int n8)
{
    int i = blockIdx.x * 256 + threadIdx.x;
    if (i >= n8) return;
    const float4 a = ((const float4*)x)[2*i];
    const float4 b = ((const float4*)x)[2*i+1];
    u16 o[8] = { f2bf(a.x), f2bf(a.y), f2bf(a.z), f2bf(a.w),
                 f2bf(b.x), f2bf(b.y), f2bf(b.z), f2bf(b.w) };
    ((uint4*)xb)[i] = *(const uint4*)o;
}

// ---------------------------------------------------------------------------
// Wq/Wk/Wv [job][d=2304][h=256] fp32  ->  Wt1 [c=4096][d=2304] bf16 (B^T)
// ---------------------------------------------------------------------------
__global__ __launch_bounds__(256) void wqkv_t_kernel(
    const float* __restrict__ Wq, const float* __restrict__ Wk,
    const float* __restrict__ Wv, u16* __restrict__ Wt)
{
    __shared__ float t[32][33];
    const int j = blockIdx.z;
    const float* W = (j < 8)  ? Wq + (size_t)j*HIDDEN*HEAD_DIM
                   : (j < 12) ? Wk + (size_t)(j-8)*HIDDEN*HEAD_DIM
                              : Wv + (size_t)(j-12)*HIDDEN*HEAD_DIM;
    const int d0 = blockIdx.x * 32, h0 = blockIdx.y * 32;
    const int tx = threadIdx.x & 31, ty = threadIdx.x >> 5;
    #pragma unroll
    for (int i = 0; i < 4; i++)
        t[ty + i*8][tx] = W[(size_t)(d0 + ty + i*8)*HEAD_DIM + h0 + tx];
    __syncthreads();
    #pragma unroll
    for (int i = 0; i < 4; i++)
        Wt[(size_t)(j*256 + h0 + ty + i*8)*HIDDEN + d0 + tx] = f2bf(t[tx][ty + i*8]);
}

// ---------------------------------------------------------------------------
// Wo flat [k=2048][d=2304] fp32 -> Wot [d=2304][k=2048] bf16 (B^T)
// ---------------------------------------------------------------------------
__global__ __launch_bounds__(256) void wo_t_kernel(
    const float* __restrict__ Wo, u16* __restrict__ Wot)
{
    __shared__ float t[32][33];
    const int k0 = blockIdx.x * 32, d0 = blockIdx.y * 32;
    const int tx = threadIdx.x & 31, ty = threadIdx.x >> 5;
    #pragma unroll
    for (int i = 0; i < 4; i++)
        t[ty + i*8][tx] = Wo[(size_t)(k0 + ty + i*8)*HIDDEN + d0 + tx];
    __syncthreads();
    #pragma unroll
    for (int i = 0; i < 4; i++)
        Wot[(size_t)(d0 + ty + i*8)*(N_Q*HEAD_DIM) + k0 + tx] = f2bf(t[tx][ty + i*8]);
}

// ---------------------------------------------------------------------------
// bf16 MFMA GEMM: C[M][N] = A[M][K] @ B[K][N], B given as Bt[N][K].
// 128x128 tile, BK=32, 4 waves each 64x64 (4x4 of 16x16x32 MFMA).
// ---------------------------------------------------------------------------
template<typename OutT>
__global__ __launch_bounds__(256) void gemm_bf16_kernel(
    const u16* __restrict__ A, const u16* __restrict__ Bt,
    OutT* __restrict__ C, int M, int N, int K)
{
    __shared__ u16 As[128*40];
    __shared__ u16 Bs[128*40];
    const int m0 = blockIdx.y * 128;
    const int n0 = blockIdx.x * 128;
    const int tid  = threadIdx.x;
    const int lane = tid & 63;
    const int wave = tid >> 6;
    const int wm = (wave & 1) * 64;
    const int wn = (wave >> 1) * 64;
    const int l16  = lane & 15;
    const int quad = lane >> 4;

    const int srow = tid >> 2;
    const int kseg = tid & 3;
    const u16* Ag = A  + (size_t)(m0 + srow)*K + kseg*8;
    const u16* Bg = Bt + (size_t)(n0 + srow)*K + kseg*8;
    const size_t rowskip = (size_t)64 * K;
    u16* AsW = As + srow*40 + kseg*8;
    u16* BsW = Bs + srow*40 + kseg*8;

    const u16* ArA = As + (wm + l16)*40 + quad*8;
    const u16* BrB = Bs + (wn + l16)*40 + quad*8;

    f32x4 acc[4][4];
    #pragma unroll
    for (int i = 0; i < 4; i++)
        #pragma unroll
        for (int j = 0; j < 4; j++) acc[i][j] = (f32x4){0.f,0.f,0.f,0.f};

    for (int k0 = 0; k0 < K; k0 += 32) {
        const uint4 a0 = *(const uint4*)(Ag + k0);
        const uint4 a1 = *(const uint4*)(Ag + rowskip + k0);
        const uint4 b0 = *(const uint4*)(Bg + k0);
        const uint4 b1 = *(const uint4*)(Bg + rowskip + k0);
        __syncthreads();
        *(uint4*)AsW            = a0;
        *(uint4*)(AsW + 64*40)  = a1;
        *(uint4*)BsW            = b0;
        *(uint4*)(BsW + 64*40)  = b1;
        __syncthreads();
        bf16x8 af[4], bfr[4];
        #pragma unroll
        for (int t = 0; t < 4; t++) af[t]  = *(const bf16x8*)(ArA + t*16*40);
        #pragma unroll
        for (int t = 0; t < 4; t++) bfr[t] = *(const bf16x8*)(BrB + t*16*40);
        #pragma unroll
        for (int i = 0; i < 4; i++)
            #pragma unroll
            for (int j = 0; j < 4; j++)
                acc[i][j] = __builtin_amdgcn_mfma_f32_16x16x32_bf16(
                                af[i], bfr[j], acc[i][j], 0, 0, 0);
    }

    #pragma unroll
    for (int i = 0; i < 4; i++) {
        const int rbase = m0 + wm + i*16 + quad*4;
        #pragma unroll
        for (int j = 0; j < 4; j++) {
            const int col = n0 + wn + j*16 + l16;
            #pragma unroll
            for (int r = 0; r < 4; r++) {
                const float v = acc[i][j][r];
                if constexpr (sizeof(OutT) == 2)
                    ((u16*)C)[(size_t)(rbase + r)*N + col] = f2bf(v);
                else
                    ((float*)C)[(size_t)(rbase + r)*N + col] = v;
            }
        }
    }
}

// ---------------------------------------------------------------------------
// RoPE + q-scale epilogue -> bf16 q/k. raw [r][4096]: 0..2047 q, 2048..3071 k.
// Non-interleaved rotation (interleave permutation cancels in q.k).
// ---------------------------------------------------------------------------
__global__ __launch_bounds__(256) void rope_kernel(
    const u16* __restrict__ raw, u16* __restrict__ qb, u16* __restrict__ kbf)
{
    const int r   = blockIdx.x;
    const int pos = r & (SEQ-1);
    const int tid = threadIdx.x;
    const u16* row = raw + (size_t)r * 4096;
    const float LOG1E4 = 9.210340371976184f;

    #pragma unroll
    for (int p = tid; p < 1024; p += 256) {   // q pairs
        const int n = p >> 7, j = p & 127;
        const float lo = bf2f(row[n*256 + j]);
        const float hi = bf2f(row[n*256 + j + 128]);
        const float inv = __expf(-LOG1E4 * (float)j * (1.0f/128.0f));
        float s, c; sincosf((float)pos * inv, &s, &c);
        qb[((size_t)r*N_Q + n)*HEAD_DIM + j]       = f2bf((lo*c - hi*s) * 0.0625f);
        qb[((size_t)r*N_Q + n)*HEAD_DIM + j + 128] = f2bf((hi*c + lo*s) * 0.0625f);
    }
    #pragma unroll
    for (int p = tid; p < 512; p += 256) {    // k pairs
        const int n = p >> 7, j = p & 127;
        const float lo = bf2f(row[2048 + n*256 + j]);
        const float hi = bf2f(row[2048 + n*256 + j + 128]);
        const float inv = __expf(-LOG1E4 * (float)j * (1.0f/128.0f));
        float s, c; sincosf((float)pos * inv, &s, &c);
        kbf[((size_t)r*N_KV + n)*HEAD_DIM + j]       = f2bf(lo*c - hi*s);
        kbf[((size_t)r*N_KV + n)*HEAD_DIM + j + 128] = f2bf(hi*c + lo*s);
    }
}

// ---------------------------------------------------------------------------
// V transpose: raw v cols -> vtt[(b*4+kh)*64 + sc][h=256][s=32] bf16 tiles.
// ---------------------------------------------------------------------------
__global__ __launch_bounds__(256) void vtrans_kernel(
    const u16* __restrict__ raw, u16* __restrict__ vtt)
{
    __shared__ u16 T[32*264];
    const int blk = blockIdx.x;        // (b*4+kh)*64 + sc
    const int sc  = blk & 63;
    const int bk  = blk >> 6;
    const int b   = bk >> 2, kh = bk & 3;
    const int tid = threadIdx.x;

    const u16* rrow = raw + (size_t)(b*SEQ + sc*32)*4096 + 3072 + kh*256;
    {
        const int s = tid >> 3;
        #pragma unroll
        for (int it = 0; it < 4; it++) {
            const int seg = (tid & 7) + it*8;
            *(uint4*)&T[s*264 + seg*8] = *(const uint4*)(rrow + (size_t)s*4096 + seg*8);
        }
    }
    __syncthreads();
    u16* out = vtt + (size_t)blk*8192;
    #pragma unroll
    for (int it = 0; it < 4; it++) {
        const int o = tid + it*256;
        const int h = o >> 2, ss = o & 3;
        u16 tmp[8];
        #pragma unroll
        for (int j = 0; j < 8; j++) tmp[j] = T[(ss*8 + j)*264 + h];
        *(uint4*)(out + h*32 + ss*8) = *(const uint4*)tmp;
    }
}

// ---------------------------------------------------------------------------
// MFMA flash attention: block = 64 q-rows x 1 q-head, 4 waves x 16 rows.
// s-tiles of 32; online softmax; soft-cap 50; window 1024 causal.
// ---------------------------------------------------------------------------
#define AQT 64
__global__ __launch_bounds__(256) void attn_mfma_kernel(
    const u16* __restrict__ qb, const u16* __restrict__ kb,
    const u16* __restrict__ vtt, u16* __restrict__ ao)
{
    __shared__ u16 Ks[32*264];    // K[s][d], pad 264
    __shared__ u16 Vs[256*40];    // V^T[h][s], pad 40
    __shared__ u16 Ps[64*40];     // P[t][s], pad 40

    const int qh = blockIdx.y;
    const int kh = qh >> 1;
    const int t0 = blockIdx.x * AQT;
    const int b  = t0 >> 11;
    const int tb = t0 & (SEQ-1);
    const int tid  = threadIdx.x;
    const int wave = tid >> 6;
    const int lane = tid & 63;
    const int l16  = lane & 15;
    const int quad = lane >> 4;

    // Q A-frags in registers: A[m=l16][k=quad*8+j], 8 d-chunks
    bf16x8 qf[8];
    {
        const u16* qrow = qb + ((size_t)(t0 + wave*16 + l16)*N_Q + qh)*HEAD_DIM + quad*8;
        #pragma unroll
        for (int c = 0; c < 8; c++) qf[c] = *(const bf16x8*)(qrow + c*32);
    }

    f32x4 o[16];
    #pragma unroll
    for (int n = 0; n < 16; n++) o[n] = (f32x4){0.f,0.f,0.f,0.f};
    float m_[4], l_[4];
    #pragma unroll
    for (int r = 0; r < 4; r++) { m_[r] = -1e30f; l_[r] = 0.0f; }

    int s_begin = tb - (WINDOW-1); if (s_begin < 0) s_begin = 0;
    const int st0 = s_begin & ~31;

    const u16* kbase = kb  + ((size_t)(b*SEQ)*N_KV + kh)*HEAD_DIM;
    const u16* vbase = vtt + ((size_t)(b*N_KV + kh)*SEQ)*HEAD_DIM;

    for (int st = st0; st < tb + AQT; st += 32) {
        __syncthreads();
        {   // stage K tile [32][264]
            const int s = tid >> 3;
            const u16* krow = kbase + (size_t)(st + s)*(N_KV*HEAD_DIM);
            #pragma unroll
            for (int it = 0; it < 4; it++) {
                const int seg = (tid & 7) + it*8;
                *(uint4*)&Ks[s*264 + seg*8] = *(const uint4*)(krow + seg*8);
            }
            // stage V^T tile [256][40] from contiguous vtt tile
            const u16* vtile = vbase + (size_t)st*HEAD_DIM;
            #pragma unroll
            for (int it = 0; it < 4; it++) {
                const int idx = tid + it*256;
                const int h = idx >> 2, ss = idx & 3;
                *(uint4*)&Vs[h*40 + ss*8] = *(const uint4*)(vtile + h*32 + ss*8);
            }
        }
        __syncthreads();

        // QK^T: S[16t][32s], two 16-col frags
        f32x4 sc[2];
        #pragma unroll
        for (int sf = 0; sf < 2; sf++) {
            f32x4 a = (f32x4){0.f,0.f,0.f,0.f};
            const u16* kr = &Ks[(sf*16 + l16)*264 + quad*8];
            #pragma unroll
            for (int c = 0; c < 8; c++)
                a = __builtin_amdgcn_mfma_f32_16x16x32_bf16(
                        qf[c], *(const bf16x8*)(kr + c*32), a, 0, 0, 0);
            sc[sf] = a;
        }

        // soft-cap + mask
        float pv[2][4];
        #pragma unroll
        for (int sf = 0; sf < 2; sf++) {
            const int sg = st + sf*16 + l16;
            #pragma unroll
            for (int r = 0; r < 4; r++) {
                const int tg = tb + wave*16 + quad*4 + r;
                float xx = sc[sf][r] * 0.04f;            // 2/SOFT_CAP
                xx = fminf(fmaxf(xx, -30.f), 30.f);
                const float e = __expf(xx);
                const float cap = 50.f * (e - 1.f) / (e + 1.f);
                const bool ok = (sg <= tg) && (tg - sg < WINDOW);
                pv[sf][r] = ok ? cap : -1e30f;
            }
        }

        // online softmax per row (rows = quad*4+r, cols across l16)
        float alpha[4];
        #pragma unroll
        for (int r = 0; r < 4; r++) {
            float mx = fmaxf(pv[0][r], pv[1][r]);
            #pragma unroll
            for (int sh = 1; sh <= 8; sh <<= 1)
                mx = fmaxf(mx, __shfl_xor(mx, sh, 64));
            const float mn = fmaxf(m_[r], mx);
            alpha[r] = __expf(m_[r] - mn);
            m_[r] = mn;
            const float p0 = __expf(pv[0][r] - mn);   // masked -> 0 (or garbage-phase 1, flushed by alpha=0)
            const float p1 = __expf(pv[1][r] - mn);
            pv[0][r] = p0; pv[1][r] = p1;
            float sm = p0 + p1;
            #pragma unroll
            for (int sh = 1; sh <= 8; sh <<= 1)
                sm += __shfl_xor(sm, sh, 64);
            l_[r] = l_[r]*alpha[r] + sm;
        }

        // rescale O
        #pragma unroll
        for (int n = 0; n < 16; n++)
            #pragma unroll
            for (int r = 0; r < 4; r++) o[n][r] *= alpha[r];

        // P -> LDS (bf16), C-layout -> A-layout round trip (wave-private rows)
        #pragma unroll
        for (int sf = 0; sf < 2; sf++)
            #pragma unroll
            for (int r = 0; r < 4; r++)
                Ps[(wave*16 + quad*4 + r)*40 + sf*16 + l16] = f2bf(pv[sf][r]);

        // PV: one A-frag covers k=0..31
        const bf16x8 ap = *(const bf16x8*)&Ps[(wave*16 + l16)*40 + quad*8];
        #pragma unroll
        for (int n = 0; n < 16; n++) {
            const bf16x8 bv = *(const bf16x8*)&Vs[(n*16 + l16)*40 + quad*8];
            o[n] = __builtin_amdgcn_mfma_f32_16x16x32_bf16(ap, bv, o[n], 0, 0, 0);
        }
    }

    // epilogue: normalize, store bf16
    #pragma unroll
    for (int r = 0; r < 4; r++) {
        const int row = t0 + wave*16 + quad*4 + r;
        u16* arow = ao + ((size_t)row*N_Q + qh)*HEAD_DIM + l16;
        const float inv = 1.0f / l_[r];
        #pragma unroll
        for (int n = 0; n < 16; n++)
            arow[n*16] = f2bf(o[n][r] * inv);
    }
}

// ---------------------------------------------------------------------------
extern "C" void kernel_launch(void* const* d_in, const int* in_sizes, int n_in,
                              void* d_out, int out_size, void* d_ws, size_t ws_size,
                              hipStream_t stream)
{
    const float* x  = (const float*)d_in[0];
    // d_in[1] = attention_mask: exactly causal(tril) -> not needed.
    const float* Wq = (const float*)d_in[2];
    const float* Wk = (const float*)d_in[3];
    const float* Wv = (const float*)d_in[4];
    const float* Wo = (const float*)d_in[5];
    float* out = (float*)d_out;

    char* w = (char*)d_ws;
    u16* qbuf = (u16*)(w);                     // 16,777,216
    u16* kbuf = (u16*)(w +  16777216ull);      //  8,388,608
    u16* vtt  = (u16*)(w +  25165824ull);      //  8,388,608
    u16* aob  = (u16*)(w +  33554432ull);      // 16,777,216
    u16* xb   = (u16*)(w +  50331648ull);      // 18,874,368
    u16* wt1  = (u16*)(w +  69206016ull);      // 18,874,368
    u16* wot  = (u16*)(w +  88080384ull);      //  9,437,184
    u16* raw  = (u16*)(w +  97517568ull);      // 33,554,432 (end ~131 MB)

    const int n8 = BT*HIDDEN/8;
    convert_x_kernel<<<(n8+255)/256, 256, 0, stream>>>(x, xb, n8);
    wqkv_t_kernel<<<dim3(HIDDEN/32, HEAD_DIM/32, 16), 256, 0, stream>>>(Wq, Wk, Wv, wt1);
    wo_t_kernel<<<dim3(N_Q*HEAD_DIM/32, HIDDEN/32), 256, 0, stream>>>(Wo, wot);

    gemm_bf16_kernel<u16><<<dim3(4096/128, BT/128), 256, 0, stream>>>(
        xb, wt1, raw, BT, 4096, HIDDEN);
    rope_kernel<<<BT, 256, 0, stream>>>(raw, qbuf, kbuf);
    vtrans_kernel<<<BATCH*N_KV*64, 256, 0, stream>>>(raw, vtt);
    attn_mfma_kernel<<<dim3(BT/AQT, N_Q), 256, 0, stream>>>(qbuf, kbuf, vtt, aob);
    gemm_bf16_kernel<float><<<dim3(HIDDEN/128, BT/128), 256, 0, stream>>>(
        aob, wot, out, BT, HIDDEN, N_Q*HEAD_DIM);
}

// Round 5
// 431.365 us; speedup vs baseline: 10.3654x; 1.0897x over previous
//
#include <hip/hip_runtime.h>
#include <math.h>

#define HEAD_DIM 256
#define N_Q 8
#define N_KV 4
#define HIDDEN 2304
#define WINDOW 1024
#define BATCH 2
#define SEQ 2048
#define BT (BATCH*SEQ)      // 4096 rows total

typedef unsigned short u16;
typedef __attribute__((ext_vector_type(8))) short bf16x8;
typedef __attribute__((ext_vector_type(4))) float f32x4;

__device__ __forceinline__ u16 f2bf(float f) {
    union { float f; unsigned u; } c; c.f = f;
    unsigned r = c.u + 0x7FFF + ((c.u >> 16) & 1);   // RNE
    return (u16)(r >> 16);
}
__device__ __forceinline__ float bf2f(u16 b) {
    union { float f; unsigned u; } c; c.u = ((unsigned)b) << 16;
    return c.f;
}

// ---------------------------------------------------------------------------
// fp32 -> bf16 elementwise (x matrix), 8 elems/thread
// ---------------------------------------------------------------------------
__global__ __launch_bounds__(256) void convert_x_kernel(
    const float* __restrict__ x, u16* __restrict__ xb, int n8)
{
    int i = blockIdx.x * 256 + threadIdx.x;
    if (i >= n8) return;
    const float4 a = ((const float4*)x)[2*i];
    const float4 b = ((const float4*)x)[2*i+1];
    u16 o[8] = { f2bf(a.x), f2bf(a.y), f2bf(a.z), f2bf(a.w),
                 f2bf(b.x), f2bf(b.y), f2bf(b.z), f2bf(b.w) };
    ((uint4*)xb)[i] = *(const uint4*)o;
}

// ---------------------------------------------------------------------------
// Wq/Wk/Wv [job][d=2304][h=256] fp32  ->  Wt1 [c=4096][d=2304] bf16 (B^T)
// ---------------------------------------------------------------------------
__global__ __launch_bounds__(256) void wqkv_t_kernel(
    const float* __restrict__ Wq, const float* __restrict__ Wk,
    const float* __restrict__ Wv, u16* __restrict__ Wt)
{
    __shared__ float t[32][33];
    const int j = blockIdx.z;
    const float* W = (j < 8)  ? Wq + (size_t)j*HIDDEN*HEAD_DIM
                   : (j < 12) ? Wk + (size_t)(j-8)*HIDDEN*HEAD_DIM
                              : Wv + (size_t)(j-12)*HIDDEN*HEAD_DIM;
    const int d0 = blockIdx.x * 32, h0 = blockIdx.y * 32;
    const int tx = threadIdx.x & 31, ty = threadIdx.x >> 5;
    #pragma unroll
    for (int i = 0; i < 4; i++)
        t[ty + i*8][tx] = W[(size_t)(d0 + ty + i*8)*HEAD_DIM + h0 + tx];
    __syncthreads();
    #pragma unroll
    for (int i = 0; i < 4; i++)
        Wt[(size_t)(j*256 + h0 + ty + i*8)*HIDDEN + d0 + tx] = f2bf(t[tx][ty + i*8]);
}

// ---------------------------------------------------------------------------
// Wo flat [k=2048][d=2304] fp32 -> Wot [d=2304][k=2048] bf16 (B^T)
// ---------------------------------------------------------------------------
__global__ __launch_bounds__(256) void wo_t_kernel(
    const float* __restrict__ Wo, u16* __restrict__ Wot)
{
    __shared__ float t[32][33];
    const int k0 = blockIdx.x * 32, d0 = blockIdx.y * 32;
    const int tx = threadIdx.x & 31, ty = threadIdx.x >> 5;
    #pragma unroll
    for (int i = 0; i < 4; i++)
        t[ty + i*8][tx] = Wo[(size_t)(k0 + ty + i*8)*HIDDEN + d0 + tx];
    __syncthreads();
    #pragma unroll
    for (int i = 0; i < 4; i++)
        Wot[(size_t)(d0 + ty + i*8)*(N_Q*HEAD_DIM) + k0 + tx] = f2bf(t[tx][ty + i*8]);
}

// ---------------------------------------------------------------------------
// bf16 MFMA GEMM, m97 structure: 128x128 tile, BK=32, global_load_lds x16
// staging into unpadded [128][32] LDS. One DMA instruction = 64 lanes x 16 B
// = 1024 B = 16 rows; 4 waves x 2 calls x 16 rows = 128 rows exactly.
// ---------------------------------------------------------------------------
template<typename OutT>
__global__ __launch_bounds__(256) void gemm_bf16_kernel(
    const u16* __restrict__ A, const u16* __restrict__ Bt,
    OutT* __restrict__ C, int M, int N, int K)
{
    __shared__ u16 As[128*32];
    __shared__ u16 Bs[128*32];
    const int m0 = blockIdx.y * 128;
    const int n0 = blockIdx.x * 128;
    const int tid  = threadIdx.x;
    const int lane = tid & 63;
    const int wave = tid >> 6;
    const int wm = (wave & 1) * 64;
    const int wn = (wave >> 1) * 64;
    const int l16  = lane & 15;
    const int quad = lane >> 4;

    // staging: call c in {0,1} covers rows c*64 + wave*16 + (lane>>2), seg=lane&3
    const int srow = wave*16 + (lane >> 2);
    const int sseg = lane & 3;
    const u16* Ag = A  + (size_t)(m0 + srow)*K + sseg*8;
    const u16* Bg = Bt + (size_t)(n0 + srow)*K + sseg*8;

    const u16* ArA = As + (wm + l16)*32 + quad*8;
    const u16* BrB = Bs + (wn + l16)*32 + quad*8;

    f32x4 acc[4][4];
    #pragma unroll
    for (int i = 0; i < 4; i++)
        #pragma unroll
        for (int j = 0; j < 4; j++) acc[i][j] = (f32x4){0.f,0.f,0.f,0.f};

    for (int k0 = 0; k0 < K; k0 += 32) {
        __syncthreads();
        #pragma unroll
        for (int c = 0; c < 2; c++) {
            __builtin_amdgcn_global_load_lds(
                (const __attribute__((address_space(1))) unsigned int*)(Ag + (size_t)c*64*K + k0),
                (__attribute__((address_space(3))) unsigned int*)&As[(c*64 + wave*16)*32],
                16, 0, 0);
            __builtin_amdgcn_global_load_lds(
                (const __attribute__((address_space(1))) unsigned int*)(Bg + (size_t)c*64*K + k0),
                (__attribute__((address_space(3))) unsigned int*)&Bs[(c*64 + wave*16)*32],
                16, 0, 0);
        }
        __syncthreads();
        bf16x8 af[4], bfr[4];
        #pragma unroll
        for (int t = 0; t < 4; t++) af[t]  = *(const bf16x8*)(ArA + t*16*32);
        #pragma unroll
        for (int t = 0; t < 4; t++) bfr[t] = *(const bf16x8*)(BrB + t*16*32);
        #pragma unroll
        for (int i = 0; i < 4; i++)
            #pragma unroll
            for (int j = 0; j < 4; j++)
                acc[i][j] = __builtin_amdgcn_mfma_f32_16x16x32_bf16(
                                af[i], bfr[j], acc[i][j], 0, 0, 0);
    }

    #pragma unroll
    for (int i = 0; i < 4; i++) {
        const int rbase = m0 + wm + i*16 + quad*4;
        #pragma unroll
        for (int j = 0; j < 4; j++) {
            const int col = n0 + wn + j*16 + l16;
            #pragma unroll
            for (int r = 0; r < 4; r++) {
                const float v = acc[i][j][r];
                if constexpr (sizeof(OutT) == 2)
                    ((u16*)C)[(size_t)(rbase + r)*N + col] = f2bf(v);
                else
                    ((float*)C)[(size_t)(rbase + r)*N + col] = v;
            }
        }
    }
}

// ---------------------------------------------------------------------------
// RoPE + q-scale epilogue -> bf16 q/k. raw [r][4096]: 0..2047 q, 2048..3071 k.
// ---------------------------------------------------------------------------
__global__ __launch_bounds__(256) void rope_kernel(
    const u16* __restrict__ raw, u16* __restrict__ qb, u16* __restrict__ kbf)
{
    const int r   = blockIdx.x;
    const int pos = r & (SEQ-1);
    const int tid = threadIdx.x;
    const u16* row = raw + (size_t)r * 4096;
    const float LOG1E4 = 9.210340371976184f;

    #pragma unroll
    for (int p = tid; p < 1024; p += 256) {   // q pairs
        const int n = p >> 7, j = p & 127;
        const float lo = bf2f(row[n*256 + j]);
        const float hi = bf2f(row[n*256 + j + 128]);
        const float inv = __expf(-LOG1E4 * (float)j * (1.0f/128.0f));
        float s, c; sincosf((float)pos * inv, &s, &c);
        qb[((size_t)r*N_Q + n)*HEAD_DIM + j]       = f2bf((lo*c - hi*s) * 0.0625f);
        qb[((size_t)r*N_Q + n)*HEAD_DIM + j + 128] = f2bf((hi*c + lo*s) * 0.0625f);
    }
    #pragma unroll
    for (int p = tid; p < 512; p += 256) {    // k pairs
        const int n = p >> 7, j = p & 127;
        const float lo = bf2f(row[2048 + n*256 + j]);
        const float hi = bf2f(row[2048 + n*256 + j + 128]);
        const float inv = __expf(-LOG1E4 * (float)j * (1.0f/128.0f));
        float s, c; sincosf((float)pos * inv, &s, &c);
        kbf[((size_t)r*N_KV + n)*HEAD_DIM + j]       = f2bf(lo*c - hi*s);
        kbf[((size_t)r*N_KV + n)*HEAD_DIM + j + 128] = f2bf(hi*c + lo*s);
    }
}

// ---------------------------------------------------------------------------
// V transpose: raw v cols -> vtt[(b*4+kh)*64 + sc][h=256][s=32] bf16 tiles.
// ---------------------------------------------------------------------------
__global__ __launch_bounds__(256) void vtrans_kernel(
    const u16* __restrict__ raw, u16* __restrict__ vtt)
{
    __shared__ u16 T[32*264];
    const int blk = blockIdx.x;
    const int sc  = blk & 63;
    const int bk  = blk >> 6;
    const int b   = bk >> 2, kh = bk & 3;
    const int tid = threadIdx.x;

    const u16* rrow = raw + (size_t)(b*SEQ + sc*32)*4096 + 3072 + kh*256;
    {
        const int s = tid >> 3;
        #pragma unroll
        for (int it = 0; it < 4; it++) {
            const int seg = (tid & 7) + it*8;
            *(uint4*)&T[s*264 + seg*8] = *(const uint4*)(rrow + (size_t)s*4096 + seg*8);
        }
    }
    __syncthreads();
    u16* out = vtt + (size_t)blk*8192;
    #pragma unroll
    for (int it = 0; it < 4; it++) {
        const int o = tid + it*256;
        const int h = o >> 2, ss = o & 3;
        u16 tmp[8];
        #pragma unroll
        for (int j = 0; j < 8; j++) tmp[j] = T[(ss*8 + j)*264 + h];
        *(uint4*)(out + h*32 + ss*8) = *(const uint4*)tmp;
    }
}

// ---------------------------------------------------------------------------
// MFMA flash attention, fixed-max softmax (soft-cap bounds logits to +-50, so
// max := 50 is exact-safe): p = exp(cap-50) = exp(-100/(e^{S/25}+1)).
// No running max, no alpha rescale, one sum-reduction at the end.
// ---------------------------------------------------------------------------
#define AQT 64
__global__ __launch_bounds__(256) void attn_mfma_kernel(
    const u16* __restrict__ qb, const u16* __restrict__ kb,
    const u16* __restrict__ vtt, u16* __restrict__ ao)
{
    __shared__ u16 Ks[32*264];    // K[s][d], pad 264
    __shared__ u16 Vs[256*40];    // V^T[h][s], pad 40
    __shared__ u16 Ps[64*40];     // P[t][s], pad 40

    const int qh = blockIdx.y;
    const int kh = qh >> 1;
    const int t0 = blockIdx.x * AQT;
    const int b  = t0 >> 11;
    const int tb = t0 & (SEQ-1);
    const int tid  = threadIdx.x;
    const int wave = tid >> 6;
    const int lane = tid & 63;
    const int l16  = lane & 15;
    const int quad = lane >> 4;

    bf16x8 qf[8];
    {
        const u16* qrow = qb + ((size_t)(t0 + wave*16 + l16)*N_Q + qh)*HEAD_DIM + quad*8;
        #pragma unroll
        for (int c = 0; c < 8; c++) qf[c] = *(const bf16x8*)(qrow + c*32);
    }

    f32x4 o[16];
    #pragma unroll
    for (int n = 0; n < 16; n++) o[n] = (f32x4){0.f,0.f,0.f,0.f};
    float lpart[4] = {0.f, 0.f, 0.f, 0.f};

    int s_begin = tb - (WINDOW-1); if (s_begin < 0) s_begin = 0;
    const int st0 = s_begin & ~31;

    const u16* kbase = kb  + ((size_t)(b*SEQ)*N_KV + kh)*HEAD_DIM;
    const u16* vbase = vtt + ((size_t)(b*N_KV + kh)*SEQ)*HEAD_DIM;

    for (int st = st0; st < tb + AQT; st += 32) {
        __syncthreads();
        {   // stage K tile [32][264]
            const int s = tid >> 3;
            const u16* krow = kbase + (size_t)(st + s)*(N_KV*HEAD_DIM);
            #pragma unroll
            for (int it = 0; it < 4; it++) {
                const int seg = (tid & 7) + it*8;
                *(uint4*)&Ks[s*264 + seg*8] = *(const uint4*)(krow + seg*8);
            }
            const u16* vtile = vbase + (size_t)st*HEAD_DIM;
            #pragma unroll
            for (int it = 0; it < 4; it++) {
                const int idx = tid + it*256;
                const int h = idx >> 2, ss = idx & 3;
                *(uint4*)&Vs[h*40 + ss*8] = *(const uint4*)(vtile + h*32 + ss*8);
            }
        }
        __syncthreads();

        // QK^T: S[16t][32s]
        f32x4 sc[2];
        #pragma unroll
        for (int sf = 0; sf < 2; sf++) {
            f32x4 a = (f32x4){0.f,0.f,0.f,0.f};
            const u16* kr = &Ks[(sf*16 + l16)*264 + quad*8];
            #pragma unroll
            for (int c = 0; c < 8; c++)
                a = __builtin_amdgcn_mfma_f32_16x16x32_bf16(
                        qf[c], *(const bf16x8*)(kr + c*32), a, 0, 0, 0);
            sc[sf] = a;
        }

        // fused soft-cap + fixed-max softmax
        #pragma unroll
        for (int sf = 0; sf < 2; sf++) {
            const int sg = st + sf*16 + l16;
            #pragma unroll
            for (int r = 0; r < 4; r++) {
                const int tg = tb + wave*16 + quad*4 + r;
                const float e1 = __expf(sc[sf][r] * 0.04f);       // e^{S/25}
                float p = __expf(-100.0f / (e1 + 1.0f));          // exp(cap-50)
                const bool ok = (sg <= tg) && (tg - sg < WINDOW);
                p = ok ? p : 0.0f;
                lpart[r] += p;
                Ps[(wave*16 + quad*4 + r)*40 + sf*16 + l16] = f2bf(p);
            }
        }

        // PV (Ps rows are wave-private; no barrier needed)
        const bf16x8 ap = *(const bf16x8*)&Ps[(wave*16 + l16)*40 + quad*8];
        #pragma unroll
        for (int n = 0; n < 16; n++) {
            const bf16x8 bv = *(const bf16x8*)&Vs[(n*16 + l16)*40 + quad*8];
            o[n] = __builtin_amdgcn_mfma_f32_16x16x32_bf16(ap, bv, o[n], 0, 0, 0);
        }
    }

    // single row-sum reduction across the 16 columns (same-quad lanes)
    float inv[4];
    #pragma unroll
    for (int r = 0; r < 4; r++) {
        float s = lpart[r];
        #pragma unroll
        for (int sh = 1; sh <= 8; sh <<= 1) s += __shfl_xor(s, sh, 64);
        inv[r] = 1.0f / (s + 1e-30f);
    }

    #pragma unroll
    for (int r = 0; r < 4; r++) {
        const int row = t0 + wave*16 + quad*4 + r;
        u16* arow = ao + ((size_t)row*N_Q + qh)*HEAD_DIM + l16;
        #pragma unroll
        for (int n = 0; n < 16; n++)
            arow[n*16] = f2bf(o[n][r] * inv[r]);
    }
}

// ---------------------------------------------------------------------------
extern "C" void kernel_launch(void* const* d_in, const int* in_sizes, int n_in,
                              void* d_out, int out_size, void* d_ws, size_t ws_size,
                              hipStream_t stream)
{
    const float* x  = (const float*)d_in[0];
    // d_in[1] = attention_mask: exactly causal(tril) -> not needed.
    const float* Wq = (const float*)d_in[2];
    const float* Wk = (const float*)d_in[3];
    const float* Wv = (const float*)d_in[4];
    const float* Wo = (const float*)d_in[5];
    float* out = (float*)d_out;

    char* w = (char*)d_ws;
    u16* qbuf = (u16*)(w);                     // 16,777,216
    u16* kbuf = (u16*)(w +  16777216ull);      //  8,388,608
    u16* vtt  = (u16*)(w +  25165824ull);      //  8,388,608
    u16* aob  = (u16*)(w +  33554432ull);      // 16,777,216
    u16* xb   = (u16*)(w +  50331648ull);      // 18,874,368
    u16* wt1  = (u16*)(w +  69206016ull);      // 18,874,368
    u16* wot  = (u16*)(w +  88080384ull);      //  9,437,184
    u16* raw  = (u16*)(w +  97517568ull);      // 33,554,432 (end ~131 MB)

    const int n8 = BT*HIDDEN/8;
    convert_x_kernel<<<(n8+255)/256, 256, 0, stream>>>(x, xb, n8);
    wqkv_t_kernel<<<dim3(HIDDEN/32, HEAD_DIM/32, 16), 256, 0, stream>>>(Wq, Wk, Wv, wt1);
    wo_t_kernel<<<dim3(N_Q*HEAD_DIM/32, HIDDEN/32), 256, 0, stream>>>(Wo, wot);

    gemm_bf16_kernel<u16><<<dim3(4096/128, BT/128), 256, 0, stream>>>(
        xb, wt1, raw, BT, 4096, HIDDEN);
    rope_kernel<<<BT, 256, 0, stream>>>(raw, qbuf, kbuf);
    vtrans_kernel<<<BATCH*N_KV*64, 256, 0, stream>>>(raw, vtt);
    attn_mfma_kernel<<<dim3(BT/AQT, N_Q), 256, 0, stream>>>(qbuf, kbuf, vtt, aob);
    gemm_bf16_kernel<float><<<dim3(HIDDEN/128, BT/128), 256, 0, stream>>>(
        aob, wot, out, BT, HIDDEN, N_Q*HEAD_DIM);
}

// Round 6
// 415.429 us; speedup vs baseline: 10.7631x; 1.0384x over previous
//
#include <hip/hip_runtime.h>
#include <math.h>

#define HEAD_DIM 256
#define N_Q 8
#define N_KV 4
#define HIDDEN 2304
#define WINDOW 1024
#define BATCH 2
#define SEQ 2048
#define BT (BATCH*SEQ)      // 4096 rows total

typedef unsigned short u16;
typedef __attribute__((ext_vector_type(8))) short bf16x8;
typedef __attribute__((ext_vector_type(4))) float f32x4;

__device__ __forceinline__ u16 f2bf(float f) {
    union { float f; unsigned u; } c; c.f = f;
    unsigned r = c.u + 0x7FFF + ((c.u >> 16) & 1);   // RNE
    return (u16)(r >> 16);
}
__device__ __forceinline__ float bf2f(u16 b) {
    union { float f; unsigned u; } c; c.u = ((unsigned)b) << 16;
    return c.f;
}

// ---------------------------------------------------------------------------
// fp32 -> bf16 elementwise (x matrix), 8 elems/thread
// ---------------------------------------------------------------------------
__global__ __launch_bounds__(256) void convert_x_kernel(
    const float* __restrict__ x, u16* __restrict__ xb, int n8)
{
    int i = blockIdx.x * 256 + threadIdx.x;
    if (i >= n8) return;
    const float4 a = ((const float4*)x)[2*i];
    const float4 b = ((const float4*)x)[2*i+1];
    u16 o[8] = { f2bf(a.x), f2bf(a.y), f2bf(a.z), f2bf(a.w),
                 f2bf(b.x), f2bf(b.y), f2bf(b.z), f2bf(b.w) };
    ((uint4*)xb)[i] = *(const uint4*)o;
}

// ---------------------------------------------------------------------------
// Wq/Wk/Wv [job][d=2304][h=256] fp32 -> Wt1 [c=4096][d=2304] bf16 (B^T).
// 64x64 tiles, float4 loads, uint4 (8x bf16) stores.
// ---------------------------------------------------------------------------
__global__ __launch_bounds__(256) void wqkv_t_kernel(
    const float* __restrict__ Wq, const float* __restrict__ Wk,
    const float* __restrict__ Wv, u16* __restrict__ Wt)
{
    __shared__ float t[64][65];
    const int j = blockIdx.z;
    const float* W = (j < 8)  ? Wq + (size_t)j*HIDDEN*HEAD_DIM
                   : (j < 12) ? Wk + (size_t)(j-8)*HIDDEN*HEAD_DIM
                              : Wv + (size_t)(j-12)*HIDDEN*HEAD_DIM;
    const int d0 = blockIdx.x * 64, h0 = blockIdx.y * 64;
    const int tid = threadIdx.x;
    {
        const int r = tid >> 4, c4 = tid & 15;
        #pragma unroll
        for (int rr = r; rr < 64; rr += 16) {
            const float4 v = *(const float4*)(W + (size_t)(d0+rr)*HEAD_DIM + h0 + c4*4);
            t[rr][c4*4+0] = v.x; t[rr][c4*4+1] = v.y;
            t[rr][c4*4+2] = v.z; t[rr][c4*4+3] = v.w;
        }
    }
    __syncthreads();
    {
        const int hh = tid >> 2;
        #pragma unroll
        for (int it = 0; it < 2; it++) {
            const int chunk = (tid & 3) + it*4;
            u16 tmp[8];
            #pragma unroll
            for (int jj = 0; jj < 8; jj++) tmp[jj] = f2bf(t[chunk*8+jj][hh]);
            *(uint4*)&Wt[(size_t)(j*256 + h0 + hh)*HIDDEN + d0 + chunk*8] = *(const uint4*)tmp;
        }
    }
}

// ---------------------------------------------------------------------------
// Wo flat [k=2048][d=2304] fp32 -> Wot [d=2304][k=2048] bf16 (B^T). 64x64.
// ---------------------------------------------------------------------------
__global__ __launch_bounds__(256) void wo_t_kernel(
    const float* __restrict__ Wo, u16* __restrict__ Wot)
{
    __shared__ float t[64][65];
    const int k0 = blockIdx.x * 64, d0 = blockIdx.y * 64;
    const int tid = threadIdx.x;
    {
        const int r = tid >> 4, c4 = tid & 15;
        #pragma unroll
        for (int rr = r; rr < 64; rr += 16) {
            const float4 v = *(const float4*)(Wo + (size_t)(k0+rr)*HIDDEN + d0 + c4*4);
            t[rr][c4*4+0] = v.x; t[rr][c4*4+1] = v.y;
            t[rr][c4*4+2] = v.z; t[rr][c4*4+3] = v.w;
        }
    }
    __syncthreads();
    {
        const int dd = tid >> 2;
        #pragma unroll
        for (int it = 0; it < 2; it++) {
            const int chunk = (tid & 3) + it*4;
            u16 tmp[8];
            #pragma unroll
            for (int jj = 0; jj < 8; jj++) tmp[jj] = f2bf(t[chunk*8+jj][dd]);
            *(uint4*)&Wot[(size_t)(d0 + dd)*(N_Q*HEAD_DIM) + k0 + chunk*8] = *(const uint4*)tmp;
        }
    }
}

// ---------------------------------------------------------------------------
// bf16 MFMA GEMM: 128x128 tile, BK=64, global_load_lds x16 staging into
// XOR-swizzled [128][64] LDS (row chunk g stored at pos g^(row&7); DMA lane
// fetches global chunk (lane&7)^(lane>>3) so the permutation is baked in).
// One DMA = 64 lanes x 16 B = 8 rows; 4 waves x 4 calls x 8 rows = 128.
// ---------------------------------------------------------------------------
template<typename OutT>
__global__ __launch_bounds__(256) void gemm_bf16_kernel(
    const u16* __restrict__ A, const u16* __restrict__ Bt,
    OutT* __restrict__ C, int M, int N, int K)
{
    __shared__ u16 As[128*64];
    __shared__ u16 Bs[128*64];
    const int m0 = blockIdx.y * 128;
    const int n0 = blockIdx.x * 128;
    const int tid  = threadIdx.x;
    const int lane = tid & 63;
    const int wave = tid >> 6;
    const int wm = (wave & 1) * 64;
    const int wn = (wave >> 1) * 64;
    const int l16  = lane & 15;
    const int quad = lane >> 4;

    const int srow8  = lane >> 3;                  // 0..7
    const int schunk = (lane & 7) ^ srow8;         // xor-swizzled source chunk
    const u16* Ag = A  + (size_t)(m0 + wave*8 + srow8)*K + schunk*8;
    const u16* Bg = Bt + (size_t)(n0 + wave*8 + srow8)*K + schunk*8;

    const int axor = l16 & 7;
    const u16* ArA = As + (wm + l16)*64;
    const u16* BrB = Bs + (wn + l16)*64;

    f32x4 acc[4][4];
    #pragma unroll
    for (int i = 0; i < 4; i++)
        #pragma unroll
        for (int j = 0; j < 4; j++) acc[i][j] = (f32x4){0.f,0.f,0.f,0.f};

    for (int k0 = 0; k0 < K; k0 += 64) {
        __syncthreads();
        #pragma unroll
        for (int c = 0; c < 4; c++) {
            __builtin_amdgcn_global_load_lds(
                (const __attribute__((address_space(1))) unsigned int*)(Ag + (size_t)c*32*K + k0),
                (__attribute__((address_space(3))) unsigned int*)&As[(c*32 + wave*8)*64],
                16, 0, 0);
            __builtin_amdgcn_global_load_lds(
                (const __attribute__((address_space(1))) unsigned int*)(Bg + (size_t)c*32*K + k0),
                (__attribute__((address_space(3))) unsigned int*)&Bs[(c*32 + wave*8)*64],
                16, 0, 0);
        }
        __syncthreads();
        #pragma unroll
        for (int kk = 0; kk < 2; kk++) {
            bf16x8 af[4], bfr[4];
            #pragma unroll
            for (int t = 0; t < 4; t++)
                af[t]  = *(const bf16x8*)(ArA + t*16*64 + (((kk<<2)|quad) ^ axor)*8);
            #pragma unroll
            for (int t = 0; t < 4; t++)
                bfr[t] = *(const bf16x8*)(BrB + t*16*64 + (((kk<<2)|quad) ^ axor)*8);
            #pragma unroll
            for (int i = 0; i < 4; i++)
                #pragma unroll
                for (int j = 0; j < 4; j++)
                    acc[i][j] = __builtin_amdgcn_mfma_f32_16x16x32_bf16(
                                    af[i], bfr[j], acc[i][j], 0, 0, 0);
        }
    }

    #pragma unroll
    for (int i = 0; i < 4; i++) {
        const int rbase = m0 + wm + i*16 + quad*4;
        #pragma unroll
        for (int j = 0; j < 4; j++) {
            const int col = n0 + wn + j*16 + l16;
            #pragma unroll
            for (int r = 0; r < 4; r++) {
                const float v = acc[i][j][r];
                if constexpr (sizeof(OutT) == 2)
                    ((u16*)C)[(size_t)(rbase + r)*N + col] = f2bf(v);
                else
                    ((float*)C)[(size_t)(rbase + r)*N + col] = v;
            }
        }
    }
}

// ---------------------------------------------------------------------------
// RoPE + q-scale epilogue -> bf16 q/k. raw [r][4096]: 0..2047 q, 2048..3071 k.
// ---------------------------------------------------------------------------
__global__ __launch_bounds__(256) void rope_kernel(
    const u16* __restrict__ raw, u16* __restrict__ qb, u16* __restrict__ kbf)
{
    const int r   = blockIdx.x;
    const int pos = r & (SEQ-1);
    const int tid = threadIdx.x;
    const u16* row = raw + (size_t)r * 4096;
    const float LOG1E4 = 9.210340371976184f;

    #pragma unroll
    for (int p = tid; p < 1024; p += 256) {   // q pairs
        const int n = p >> 7, j = p & 127;
        const float lo = bf2f(row[n*256 + j]);
        const float hi = bf2f(row[n*256 + j + 128]);
        const float inv = __expf(-LOG1E4 * (float)j * (1.0f/128.0f));
        float s, c; sincosf((float)pos * inv, &s, &c);
        qb[((size_t)r*N_Q + n)*HEAD_DIM + j]       = f2bf((lo*c - hi*s) * 0.0625f);
        qb[((size_t)r*N_Q + n)*HEAD_DIM + j + 128] = f2bf((hi*c + lo*s) * 0.0625f);
    }
    #pragma unroll
    for (int p = tid; p < 512; p += 256) {    // k pairs
        const int n = p >> 7, j = p & 127;
        const float lo = bf2f(row[2048 + n*256 + j]);
        const float hi = bf2f(row[2048 + n*256 + j + 128]);
        const float inv = __expf(-LOG1E4 * (float)j * (1.0f/128.0f));
        float s, c; sincosf((float)pos * inv, &s, &c);
        kbf[((size_t)r*N_KV + n)*HEAD_DIM + j]       = f2bf(lo*c - hi*s);
        kbf[((size_t)r*N_KV + n)*HEAD_DIM + j + 128] = f2bf(hi*c + lo*s);
    }
}

// ---------------------------------------------------------------------------
// V transpose: raw v cols -> vtt tiles [h=256][s=32], s-chunk c stored at
// position c^(h&3) (bank swizzle consumed by attention's Vs fragment reads).
// ---------------------------------------------------------------------------
__global__ __launch_bounds__(256) void vtrans_kernel(
    const u16* __restrict__ raw, u16* __restrict__ vtt)
{
    __shared__ u16 T[32*264];
    const int blk = blockIdx.x;
    const int sc  = blk & 63;
    const int bk  = blk >> 6;
    const int b   = bk >> 2, kh = bk & 3;
    const int tid = threadIdx.x;

    const u16* rrow = raw + (size_t)(b*SEQ + sc*32)*4096 + 3072 + kh*256;
    {
        const int s = tid >> 3;
        #pragma unroll
        for (int it = 0; it < 4; it++) {
            const int seg = (tid & 7) + it*8;
            *(uint4*)&T[s*264 + seg*8] = *(const uint4*)(rrow + (size_t)s*4096 + seg*8);
        }
    }
    __syncthreads();
    u16* out = vtt + (size_t)blk*8192;
    #pragma unroll
    for (int it = 0; it < 4; it++) {
        const int o = tid + it*256;
        const int h = o >> 2, ss = o & 3;
        u16 tmp[8];
        #pragma unroll
        for (int j = 0; j < 8; j++) tmp[j] = T[(ss*8 + j)*264 + h];
        *(uint4*)(out + h*32 + ((ss ^ (h & 3))*8)) = *(const uint4*)tmp;
    }
}

// ---------------------------------------------------------------------------
// MFMA flash attention, fixed-max softmax. QK^T: wave w owns rows w*16..+15.
// PV: wave w owns h-cols w*64..+63 (cross-wave P via LDS + barrier).
// V staged by global_load_lds (swizzle pre-applied by vtrans).
// ---------------------------------------------------------------------------
#define AQT 64
__global__ __launch_bounds__(256) void attn_mfma_kernel(
    const u16* __restrict__ qb, const u16* __restrict__ kb,
    const u16* __restrict__ vtt, u16* __restrict__ ao)
{
    __shared__ u16 Ks[32*264];    // K[s][d], pad 264
    __shared__ u16 Vs[256*32];    // V^T[h][s-chunks swizzled], unpadded (DMA)
    __shared__ u16 Ps[64*40];     // P[t][s], pad 40
    __shared__ float lsum[64];

    const int qh = blockIdx.y;
    const int kh = qh >> 1;
    // balance swizzle: second dispatch sweep (y>=4) reverses tile order
    const int bx = ((blockIdx.y >> 2) & 1) ? (gridDim.x - 1 - (int)blockIdx.x)
                                           : (int)blockIdx.x;
    const int t0 = bx * AQT;
    const int b  = t0 >> 11;
    const int tb = t0 & (SEQ-1);
    const int tid  = threadIdx.x;
    const int wave = tid >> 6;
    const int lane = tid & 63;
    const int l16  = lane & 15;
    const int quad = lane >> 4;

    bf16x8 qf[8];
    {
        const u16* qrow = qb + ((size_t)(t0 + wave*16 + l16)*N_Q + qh)*HEAD_DIM + quad*8;
        #pragma unroll
        for (int c = 0; c < 8; c++) qf[c] = *(const bf16x8*)(qrow + c*32);
    }

    f32x4 o[4][4];    // rows i*16+quad*4+r, cols wave*64+j*16+l16
    #pragma unroll
    for (int i = 0; i < 4; i++)
        #pragma unroll
        for (int j = 0; j < 4; j++) o[i][j] = (f32x4){0.f,0.f,0.f,0.f};
    float lpart[4] = {0.f, 0.f, 0.f, 0.f};

    int s_begin = tb - (WINDOW-1); if (s_begin < 0) s_begin = 0;
    const int st0 = s_begin & ~31;

    const u16* kbase = kb  + ((size_t)(b*SEQ)*N_KV + kh)*HEAD_DIM;
    const u16* vbase = vtt + ((size_t)(b*N_KV + kh)*SEQ)*HEAD_DIM;

    for (int st = st0; st < tb + AQT; st += 32) {
        __syncthreads();
        {   // V tile via DMA: 16 KB contiguous, 4 calls/wave
            const u16* vtile = vbase + (size_t)st*HEAD_DIM;
            #pragma unroll
            for (int c = 0; c < 4; c++) {
                const int off = wave*2048 + c*512;
                __builtin_amdgcn_global_load_lds(
                    (const __attribute__((address_space(1))) unsigned int*)(vtile + off + lane*8),
                    (__attribute__((address_space(3))) unsigned int*)&Vs[off],
                    16, 0, 0);
            }
            // K tile manual (padded 264)
            const int s = tid >> 3;
            const u16* krow = kbase + (size_t)(st + s)*(N_KV*HEAD_DIM);
            #pragma unroll
            for (int it = 0; it < 4; it++) {
                const int seg = (tid & 7) + it*8;
                *(uint4*)&Ks[s*264 + seg*8] = *(const uint4*)(krow + seg*8);
            }
        }
        __syncthreads();

        // QK^T: wave rows wave*16..+15, S[16][32]
        f32x4 sc[2];
        #pragma unroll
        for (int sf = 0; sf < 2; sf++) {
            f32x4 a = (f32x4){0.f,0.f,0.f,0.f};
            const u16* kr = &Ks[(sf*16 + l16)*264 + quad*8];
            #pragma unroll
            for (int c = 0; c < 8; c++)
                a = __builtin_amdgcn_mfma_f32_16x16x32_bf16(
                        qf[c], *(const bf16x8*)(kr + c*32), a, 0, 0, 0);
            sc[sf] = a;
        }

        // fused soft-cap + fixed-max softmax, write P
        #pragma unroll
        for (int sf = 0; sf < 2; sf++) {
            const int sg = st + sf*16 + l16;
            #pragma unroll
            for (int r = 0; r < 4; r++) {
                const int tg = tb + wave*16 + quad*4 + r;
                const float e1 = __expf(sc[sf][r] * 0.04f);       // e^{S/25}
                float p = __expf(-100.0f / (e1 + 1.0f));          // exp(cap-50)
                const bool ok = (sg <= tg) && (tg - sg < WINDOW);
                p = ok ? p : 0.0f;
                lpart[r] += p;
                Ps[(wave*16 + quad*4 + r)*40 + sf*16 + l16] = f2bf(p);
            }
        }
        __syncthreads();   // Ps complete (all 64 rows)

        // PV: wave owns h-cols wave*64..+63, all 64 rows
        bf16x8 ap[4];
        #pragma unroll
        for (int i = 0; i < 4; i++)
            ap[i] = *(const bf16x8*)&Ps[(i*16 + l16)*40 + quad*8];
        #pragma unroll
        for (int j = 0; j < 4; j++) {
            const int hr = wave*64 + j*16 + l16;
            const bf16x8 bv = *(const bf16x8*)&Vs[hr*32 + ((quad ^ (l16 & 3))*8)];
            #pragma unroll
            for (int i = 0; i < 4; i++)
                o[i][j] = __builtin_amdgcn_mfma_f32_16x16x32_bf16(ap[i], bv, o[i][j], 0, 0, 0);
        }
    }

    // row sums -> LDS (QK rows are wave-owned)
    #pragma unroll
    for (int r = 0; r < 4; r++) {
        float s = lpart[r];
        #pragma unroll
        for (int sh = 1; sh <= 8; sh <<= 1) s += __shfl_xor(s, sh, 64);
        if (l16 == 0) lsum[wave*16 + quad*4 + r] = s;
    }
    __syncthreads();

    #pragma unroll
    for (int i = 0; i < 4; i++) {
        #pragma unroll
        for (int r = 0; r < 4; r++) {
            const int rl  = i*16 + quad*4 + r;
            const float inv = 1.0f / (lsum[rl] + 1e-30f);
            u16* arow = ao + ((size_t)(t0 + rl)*N_Q + qh)*HEAD_DIM + wave*64 + l16;
            #pragma unroll
            for (int j = 0; j < 4; j++)
                arow[j*16] = f2bf(o[i][j][r] * inv);
        }
    }
}

// ---------------------------------------------------------------------------
extern "C" void kernel_launch(void* const* d_in, const int* in_sizes, int n_in,
                              void* d_out, int out_size, void* d_ws, size_t ws_size,
                              hipStream_t stream)
{
    const float* x  = (const float*)d_in[0];
    // d_in[1] = attention_mask: exactly causal(tril) -> not needed.
    const float* Wq = (const float*)d_in[2];
    const float* Wk = (const float*)d_in[3];
    const float* Wv = (const float*)d_in[4];
    const float* Wo = (const float*)d_in[5];
    float* out = (float*)d_out;

    char* w = (char*)d_ws;
    u16* qbuf = (u16*)(w);                     // 16,777,216
    u16* kbuf = (u16*)(w +  16777216ull);      //  8,388,608
    u16* vtt  = (u16*)(w +  25165824ull);      //  8,388,608
    u16* aob  = (u16*)(w +  33554432ull);      // 16,777,216
    u16* xb   = (u16*)(w +  50331648ull);      // 18,874,368
    u16* wt1  = (u16*)(w +  69206016ull);      // 18,874,368
    u16* wot  = (u16*)(w +  88080384ull);      //  9,437,184
    u16* raw  = (u16*)(w +  97517568ull);      // 33,554,432 (end ~131 MB)

    const int n8 = BT*HIDDEN/8;
    convert_x_kernel<<<(n8+255)/256, 256, 0, stream>>>(x, xb, n8);
    wqkv_t_kernel<<<dim3(HIDDEN/64, HEAD_DIM/64, 16), 256, 0, stream>>>(Wq, Wk, Wv, wt1);
    wo_t_kernel<<<dim3(N_Q*HEAD_DIM/64, HIDDEN/64), 256, 0, stream>>>(Wo, wot);

    gemm_bf16_kernel<u16><<<dim3(4096/128, BT/128), 256, 0, stream>>>(
        xb, wt1, raw, BT, 4096, HIDDEN);
    rope_kernel<<<BT, 256, 0, stream>>>(raw, qbuf, kbuf);
    vtrans_kernel<<<BATCH*N_KV*64, 256, 0, stream>>>(raw, vtt);
    attn_mfma_kernel<<<dim3(BT/AQT, N_Q), 256, 0, stream>>>(qbuf, kbuf, vtt, aob);
    gemm_bf16_kernel<float><<<dim3(HIDDEN/128, BT/128), 256, 0, stream>>>(
        aob, wot, out, BT, HIDDEN, N_Q*HEAD_DIM);
}